// Round 5
// baseline (250.456 us; speedup 1.0000x reference)
//
#include <hip/hip_runtime.h>
#include <math.h>
#include <string.h>

// ============================================================================
// WaveletBasis as bf16 MFMA GEMM: M=32768(B), N=64(O), K=1024*9.
// K layout: 128 "runs" of 72 k-values, run R = features [8R,8R+8). Within a
// run, feature pair p occupies shorts [18p,18p+18):
//   [basis(f_even) n=0..7 | x_even | x_odd | basis(f_odd) n=0..7]
// Flat K32-step g: chunk c=g/9, octet j=g%9, lane-group q holds run 4c+q.
//
// ROUND 5: M=64 tile (B L2 traffic = 512 x 1.125 MB = 576 MB ~ 17us; round
// 4's M=32 doubled it to 33us — the measured regression) + 4 blocks/CU
// (single 36 KB A-buffer, 9-step chunks, 2 barriers/chunk) for cross-block
// pipe overlap (4 independent barrier domains/CU). Register budget kept
// <=128 VGPR for 4 waves/SIMD: per-step B loads, no chunk-batched prefetch.
// Threshold-compare builder (exact, host-computed boundaries) and 2-pass
// zero-conflict epilogue carried from round 4 (conflicts measured 0).
// ============================================================================

typedef __attribute__((ext_vector_type(8))) short short8;
typedef __attribute__((ext_vector_type(4))) float f32x4;

__device__ __forceinline__ unsigned int f2bf(float f) {
  unsigned int u = __float_as_uint(f);
  u += 0x7FFFu + ((u >> 16) & 1u);   // RNE; finite inputs
  return u >> 16;
}

// 4 dwords = 8 bf16 basis values (n=0..7) as a function of bucket j.
__device__ __forceinline__ void gen_basis(int j, unsigned int* d) {
  d[0] = (j < 4) ? 0x3F803F80u : 0xBF803F80u;                  // [phi=1, psi0=+-1]
  unsigned int sq1 = (j & 2) ? 0xBFB5u : 0x3FB5u;              // +-sqrt2
  d[1] = (j & 4) ? (sq1 << 16) : sq1;                          // one-hot k1=j>>2
  unsigned long long sd2 = (j & 1) ? 0xC000ull : 0x4000ull;    // +-2
  unsigned long long d23 = sd2 << ((j & 6) << 3);              // << 16*(j>>1)
  d[2] = (unsigned int)d23;
  d[3] = (unsigned int)(d23 >> 32);
}

#define BARRIER() __asm__ volatile("s_waitcnt lgkmcnt(0)\n\ts_barrier" ::: "memory")

// ---------------------------------------------------------------------------
// K1: W swizzle into MFMA B-fragment order under the run/pair K layout.
// Wsw[(g*4+t)*64 + l] = octet j=g%9 of run R=(g/9)*4+(l>>4), col o=t*16+(l&15)
// ---------------------------------------------------------------------------
__global__ __launch_bounds__(256) void build_w(const float* __restrict__ coeffs,
                                               const float* __restrict__ bw,
                                               uint4* __restrict__ Wsw) {
  const int l = threadIdx.x & 63;
  const int t = threadIdx.x >> 6;   // 0..3
  const int g = blockIdx.x;         // 0..287
  const int c = g / 9, j = g - c * 9;
  const int R = c * 4 + (l >> 4);
  const int o = t * 16 + (l & 15);
  unsigned int dwv[4];
#pragma unroll
  for (int jj = 0; jj < 8; ++jj) {
    int d = 8 * j + jj;             // run-local short index 0..71
    int p = d / 18;
    int e = d - p * 18;
    int f, n;
    if (e < 8)       { f = 8 * R + 2 * p;     n = e; }
    else if (e == 8) { f = 8 * R + 2 * p;     n = 8; }
    else if (e == 9) { f = 8 * R + 2 * p + 1; n = 8; }
    else             { f = 8 * R + 2 * p + 1; n = e - 10; }
    float v = (n < 8) ? coeffs[(f * 64 + o) * 8 + n] : bw[f * 64 + o];
    unsigned int h = f2bf(v);
    if (jj & 1) dwv[jj >> 1] |= h << 16; else dwv[jj >> 1] = h;
  }
  uint4 qq; qq.x = dwv[0]; qq.y = dwv[1]; qq.z = dwv[2]; qq.w = dwv[3];
  Wsw[(g * 4 + t) * 64 + l] = qq;
}

// ---------------------------------------------------------------------------
// One K32-step: 4 B-frags from L2, 4 A-frags from LDS, 16 MFMAs.
// ---------------------------------------------------------------------------
__device__ __forceinline__ void mfma_step(const uint4* __restrict__ Albuf,
                                          const uint4* __restrict__ Wsw,
                                          f32x4* acc, int g, int s,
                                          int q, int mm, int l) {
  const uint4* wp = Wsw + (size_t)g * 256 + l;
  uint4 b0 = wp[0], b1 = wp[64], b2 = wp[128], b3 = wp[192];
  const uint4* ab = Albuf + (s * 4 + q) * 64 + mm;
  short8 a0 = __builtin_bit_cast(short8, ab[0]);
  short8 a1 = __builtin_bit_cast(short8, ab[16]);
  short8 a2 = __builtin_bit_cast(short8, ab[32]);
  short8 a3 = __builtin_bit_cast(short8, ab[48]);
  short8 B0 = __builtin_bit_cast(short8, b0);
  short8 B1 = __builtin_bit_cast(short8, b1);
  short8 B2 = __builtin_bit_cast(short8, b2);
  short8 B3 = __builtin_bit_cast(short8, b3);
  acc[0]  = __builtin_amdgcn_mfma_f32_16x16x32_bf16(a0, B0, acc[0],  0, 0, 0);
  acc[1]  = __builtin_amdgcn_mfma_f32_16x16x32_bf16(a0, B1, acc[1],  0, 0, 0);
  acc[2]  = __builtin_amdgcn_mfma_f32_16x16x32_bf16(a0, B2, acc[2],  0, 0, 0);
  acc[3]  = __builtin_amdgcn_mfma_f32_16x16x32_bf16(a0, B3, acc[3],  0, 0, 0);
  acc[4]  = __builtin_amdgcn_mfma_f32_16x16x32_bf16(a1, B0, acc[4],  0, 0, 0);
  acc[5]  = __builtin_amdgcn_mfma_f32_16x16x32_bf16(a1, B1, acc[5],  0, 0, 0);
  acc[6]  = __builtin_amdgcn_mfma_f32_16x16x32_bf16(a1, B2, acc[6],  0, 0, 0);
  acc[7]  = __builtin_amdgcn_mfma_f32_16x16x32_bf16(a1, B3, acc[7],  0, 0, 0);
  acc[8]  = __builtin_amdgcn_mfma_f32_16x16x32_bf16(a2, B0, acc[8],  0, 0, 0);
  acc[9]  = __builtin_amdgcn_mfma_f32_16x16x32_bf16(a2, B1, acc[9],  0, 0, 0);
  acc[10] = __builtin_amdgcn_mfma_f32_16x16x32_bf16(a2, B2, acc[10], 0, 0, 0);
  acc[11] = __builtin_amdgcn_mfma_f32_16x16x32_bf16(a2, B3, acc[11], 0, 0, 0);
  acc[12] = __builtin_amdgcn_mfma_f32_16x16x32_bf16(a3, B0, acc[12], 0, 0, 0);
  acc[13] = __builtin_amdgcn_mfma_f32_16x16x32_bf16(a3, B1, acc[13], 0, 0, 0);
  acc[14] = __builtin_amdgcn_mfma_f32_16x16x32_bf16(a3, B2, acc[14], 0, 0, 0);
  acc[15] = __builtin_amdgcn_mfma_f32_16x16x32_bf16(a3, B3, acc[15], 0, 0, 0);
}

// ---------------------------------------------------------------------------
// K2: 512 blocks x 256 thr (4 waves), 4 blocks/CU. Block = 64 rows x 64 cols.
// Chunk c = 4 runs (32 features) = 9 K32-steps = 36 KB single A-buffer.
// Builder: thread (m=tid&63, r=tid>>6) builds run 4c+r for row m.
// MFMA: wave w takes steps s in [0,9) with s%4 == (w+c)%4 (2 or 3; balanced).
// ---------------------------------------------------------------------------
__global__ __launch_bounds__(256, 4) void wavelet_gemm(const float* __restrict__ x,
                                                       const uint4* __restrict__ Wsw,
                                                       float* __restrict__ out,
                                                       int out_size,
                                                       float4 Ta, float4 Tb) {
  __shared__ uint4 Albuf[9 * 4 * 64];   // 36 KB; reused as partial-C at end
  const int tid = threadIdx.x;
  const int l = tid & 63;
  const int w = tid >> 6;            // wave 0..3
  const int q = l >> 4;
  const int mm = l & 15;
  const int m = tid & 63;            // builder row 0..63
  const int r = tid >> 6;            // builder run-in-chunk 0..3
  const long rowbase = (long)blockIdx.x * 64;

  f32x4 acc[16];
#pragma unroll
  for (int i = 0; i < 16; ++i) acc[i] = (f32x4){0.f, 0.f, 0.f, 0.f};

  const float* xrow = x + (rowbase + m) * 1024 + r * 8;
  const int wboff = r * 64 + m;      // Albuf[(gg*4 + r)*64 + m] = wboff + gg*256

  float4 xa = *(const float4*)(xrow);
  float4 xb = *(const float4*)(xrow + 4);

  for (int c = 0; c < 32; ++c) {
    // ---------------- builder: 8 features (one run) -> 9 uint4 -> LDS -------
    float xv[8];
    xv[0] = xa.x; xv[1] = xa.y; xv[2] = xa.z; xv[3] = xa.w;
    xv[4] = xb.x; xv[5] = xb.y; xv[6] = xb.z; xv[7] = xb.w;
    unsigned int dw[36];
#pragma unroll
    for (int p = 0; p < 4; ++p) {
      float xe = xv[2 * p], xo = xv[2 * p + 1];
      int je = (xe >= Ta.x) + (xe >= Ta.y) + (xe >= Ta.z) + (xe >= Ta.w)
             + (xe >= Tb.x) + (xe >= Tb.y) + (xe >= Tb.z);
      int jo = (xo >= Ta.x) + (xo >= Ta.y) + (xo >= Ta.z) + (xo >= Ta.w)
             + (xo >= Tb.x) + (xo >= Tb.y) + (xo >= Tb.z);
      gen_basis(je, &dw[9 * p]);
      dw[9 * p + 4] = f2bf(xe) | (f2bf(xo) << 16);
      gen_basis(jo, &dw[9 * p + 5]);
    }
#pragma unroll
    for (int gg = 0; gg < 9; ++gg) {
      uint4 qv; qv.x = dw[4 * gg]; qv.y = dw[4 * gg + 1];
      qv.z = dw[4 * gg + 2]; qv.w = dw[4 * gg + 3];
      Albuf[wboff + gg * 256] = qv;
    }
    BARRIER();                              // A(c) visible
    if (c + 1 < 32) {                       // x prefetch rides over MFMA phase
      xa = *(const float4*)(xrow + (c + 1) * 32);
      xb = *(const float4*)(xrow + (c + 1) * 32 + 4);
    }
    // ---------------- MFMA: this wave's steps (rotated 4-way split) ---------
    const int t = (w + c) & 3;              // t=0 -> steps {t,t+4,8}, else {t,t+4}
    mfma_step(Albuf, Wsw, acc, c * 9 + t,     t,     q, mm, l);
    mfma_step(Albuf, Wsw, acc, c * 9 + t + 4, t + 4, q, mm, l);
    if (t == 0)
      mfma_step(Albuf, Wsw, acc, c * 9 + 8,   8,     q, mm, l);
    BARRIER();                              // LDS reads drained before rewrite
  }

  // ---- K-reduction epilogue, 2 passes of 8 slots, zero-conflict layout ----
  // acc slot sg = rt*4+tt: rows 16rt+4q+e, col 16tt+mm.
  float* P = (float*)Albuf;                 // pass uses 4 x 8 KB = 32 KB
  float* og = out + (size_t)rowbase * 64;
#pragma unroll
  for (int h = 0; h < 2; ++h) {
#pragma unroll
    for (int s = 0; s < 8; ++s)
      *(f32x4*)(P + w * 2048 + s * 256 + 4 * l) = acc[8 * h + s];
    BARRIER();
#pragma unroll
    for (int si = 0; si < 2; ++si) {
      const int s = 2 * w + si;             // this wave reduces slots 2w,2w+1
      f32x4 v = *(f32x4*)(P + 0 * 2048 + s * 256 + 4 * l);
      v = v + *(f32x4*)(P + 1 * 2048 + s * 256 + 4 * l);
      v = v + *(f32x4*)(P + 2 * 2048 + s * 256 + 4 * l);
      v = v + *(f32x4*)(P + 3 * 2048 + s * 256 + 4 * l);
      const int sg = 8 * h + s, rt = sg >> 2, tt = sg & 3;
#pragma unroll
      for (int e = 0; e < 4; ++e)
        og[(16 * rt + 4 * q + e) * 64 + 16 * tt + mm] = v[e];
    }
    BARRIER();                              // reads drained before pass 2
  }
  if (blockIdx.x == 0 && tid == 0) out[out_size - 1] = 0.0f;  // kl = 0
}

// ---------------------------------------------------------------------------
// Host: exact f32 bucket boundaries of the reference pipeline.
// Xk = smallest f32 x with ((float)tanh((double)x) + 1.0f)*0.5f*8.0f >= k.
// ---------------------------------------------------------------------------
static unsigned int f32key(float f) {
  unsigned int u; memcpy(&u, &f, 4);
  return (u & 0x80000000u) ? ~u : (u | 0x80000000u);
}
static float f32unkey(unsigned int k) {
  unsigned int u = (k & 0x80000000u) ? (k ^ 0x80000000u) : ~k;
  float f; memcpy(&f, &u, 4);
  return f;
}
static bool pipe_ge(float x, int k) {
  float tf = (float)tanh((double)x);
  float s = (tf + 1.0f) * 0.5f;
  float t8 = s * 8.0f;
  return t8 >= (float)k;
}
static void thresholds(float* X) {
  for (int k = 1; k <= 7; ++k) {
    unsigned int lo = f32key(-4.0f);   // P false
    unsigned int hi = f32key(4.0f);    // P true
    while (hi - lo > 1) {
      unsigned int mid = lo + (hi - lo) / 2;
      if (pipe_ge(f32unkey(mid), k)) hi = mid; else lo = mid;
    }
    X[k - 1] = f32unkey(hi);
  }
}

extern "C" void kernel_launch(void* const* d_in, const int* in_sizes, int n_in,
                              void* d_out, int out_size, void* d_ws, size_t ws_size,
                              hipStream_t stream) {
  const float* x      = (const float*)d_in[0];   // [32768,1024] f32
  const float* coeffs = (const float*)d_in[1];   // [1024,64,8] f32
  const float* bw     = (const float*)d_in[2];   // [1024,64] f32
  uint4* Wsw = (uint4*)d_ws;                     // 288*4*64*16 = 1.125 MiB
  float* out = (float*)d_out;

  float X[7];
  thresholds(X);
  float4 Ta; Ta.x = X[0]; Ta.y = X[1]; Ta.z = X[2]; Ta.w = X[3];
  float4 Tb; Tb.x = X[4]; Tb.y = X[5]; Tb.z = X[6]; Tb.w = 1e30f;

  build_w<<<288, 256, 0, stream>>>(coeffs, bw, Wsw);
  wavelet_gemm<<<512, 256, 0, stream>>>(x, (const uint4*)Wsw, out, out_size, Ta, Tb);
}